// Round 11
// baseline (44.046 us; speedup 1.0000x reference)
//
#include <hip/hip_runtime.h>
#include <stdint.h>

typedef __attribute__((ext_vector_type(4)))  int   i32x4;
typedef __attribute__((ext_vector_type(8)))  int   i32x8;
typedef __attribute__((ext_vector_type(16))) float f32x16;

#define NROWS 4096
#define DDIM  1024     // bytes per fp8 row (= 1024 elements)
#define NKT   16       // K-tiles of 64 bytes
#define GBLK  512      // 16 x 32 grid of 256x128 output tiles (full gram)
#define COS_EPS 1e-8f
#define SCL   0x7F7F7F7F   // E8M0 = 127 -> scale 1.0

__device__ __forceinline__ void gload16(const uint8_t* g, uint8_t* l) {
  __builtin_amdgcn_global_load_lds(
      (const __attribute__((address_space(1))) uint32_t*)g,
      (__attribute__((address_space(3))) uint32_t*)l, 16, 0, 0);
}

__device__ __forceinline__ i32x8 cat8(i32x4 lo, i32x4 hi) {
  i32x8 r;
  r[0] = lo[0]; r[1] = lo[1]; r[2] = lo[2]; r[3] = lo[3];
  r[4] = hi[0]; r[5] = hi[1]; r[6] = hi[2]; r[7] = hi[3];
  return r;
}

// ---------------- prep: sq, 1/norm, fp8 e4m3 copy ----------------
extern "C" __global__ void __launch_bounds__(256) prep_kernel(
    const float* __restrict__ F, uint8_t* __restrict__ Fb,
    float* __restrict__ sq, float* __restrict__ rn) {
  const int row  = blockIdx.x * 4 + (threadIdx.x >> 6);
  const int lane = threadIdx.x & 63;
  const float4* src = (const float4*)(F + (size_t)row * DDIM + lane * 16);
  float4 v[4];
#pragma unroll
  for (int i = 0; i < 4; ++i) v[i] = src[i];
  float s = 0.f;
#pragma unroll
  for (int i = 0; i < 4; ++i)
    s += v[i].x * v[i].x + v[i].y * v[i].y + v[i].z * v[i].z + v[i].w * v[i].w;
  uint32_t d[4];
#pragma unroll
  for (int i = 0; i < 4; ++i) {
    int w = __builtin_amdgcn_cvt_pk_fp8_f32(v[i].x, v[i].y, 0, false);
    w = __builtin_amdgcn_cvt_pk_fp8_f32(v[i].z, v[i].w, w, true);
    d[i] = (uint32_t)w;
  }
  *(uint4*)(Fb + (size_t)row * DDIM + lane * 16) = make_uint4(d[0], d[1], d[2], d[3]);
#pragma unroll
  for (int off = 32; off; off >>= 1) s += __shfl_down(s, off);
  if (lane == 0) {
    sq[row] = s;
    rn[row] = 1.0f / fmaxf(sqrtf(s), COS_EPS);
  }
}

// ---------------- fused gram: fp8 MX, 256x128 tiles, 2 blocks/CU -----------
// 512 blocks, 8 waves (4M x 2N), wave = 64x64 out (acc 2x2 f32x16 = 64 VGPR).
// 3-slot LDS ring (3 x 24KB = 72KB) -> 2 blocks/CU. Per K-tile (64 B):
// {8 ds_read (grouped lo/hi) | 3 gload_lds (stage kt+2) | vmcnt(3) |
//  4 MFMA (setprio) | s_barrier}. One barrier per K-tile; cross-block TLP
// hides the stall. Row-pair LDS layout + granule XOR as R10 (correctness-
// verified); reads grouped so consecutive ds_reads share a bank footprint.
extern "C" __global__ void __launch_bounds__(512, 4) gram_kernel(
    const uint8_t* __restrict__ Fb, const float* __restrict__ sq,
    const float* __restrict__ rn, const int* __restrict__ y,
    float* __restrict__ partials) {
  __shared__ __align__(16) uint8_t As[3][16384];  // 256 rows x 64B per slot
  __shared__ __align__(16) uint8_t Bs[3][8192];   // 128 rows x 64B per slot

  // XCD-aware bijection (512 = 8*64)
  const int wg = (int)(blockIdx.x & 7) * 64 + (int)(blockIdx.x >> 3);
  const int bi = wg >> 5, bj = wg & 31;           // bi: 256-row, bj: 128-col

  const int tid  = threadIdx.x;
  const int lane = tid & 63;
  const int wid  = tid >> 6;
  const int wr   = wid >> 1;      // 0..3 : 64-row group
  const int wc   = wid & 1;       // 0..1 : 64-col group
  const int kg   = lane >> 5;
  const int r32  = lane & 31;

  // staging source decode (inverse of row-pair + granule-XOR LDS map)
  const int hc   = (tid & 7) ^ ((tid >> 3) & 7);
  const int srow = 2 * (tid >> 3) + ((hc >> 2) & 1);   // 0..127
  const int scol = (hc & 3) * 16;
  const uint8_t* gA0 = Fb + (size_t)(bi * 256 + srow) * DDIM + scol;
  const uint8_t* gA1 = gA0 + (size_t)128 * DDIM;
  const uint8_t* gB0 = Fb + (size_t)(bj * 128 + srow) * DDIM + scol;
  uint8_t* ldsA = &As[0][0] + tid * 16;
  uint8_t* ldsB = &Bs[0][0] + tid * 16;

  // fragment read offsets (lo granule; hi = lo ^ 16)
  int offA[2], offB[2];
#pragma unroll
  for (int mt = 0; mt < 2; ++mt) {
    const int R = wr * 64 + mt * 32 + r32;
    const int u = R >> 1, h = R & 1;
    offA[mt] = u * 128 + (((h << 2) + 2 * kg) ^ (u & 7)) * 16;
  }
#pragma unroll
  for (int nb = 0; nb < 2; ++nb) {
    const int R = wc * 64 + nb * 32 + r32;
    const int u = R >> 1, h = R & 1;
    offB[nb] = u * 128 + (((h << 2) + 2 * kg) ^ (u & 7)) * 16;
  }

  f32x16 acc[2][2] = {};

#define STAGE(kt2) do {                                                     \
    const int _sl = (kt2) % 3;                                              \
    gload16(gA0 + (kt2) * 64, ldsA + _sl * 16384);                          \
    gload16(gA1 + (kt2) * 64, ldsA + _sl * 16384 + 8192);                   \
    gload16(gB0 + (kt2) * 64, ldsB + _sl * 8192);                           \
  } while (0)

  // prologue: K-tiles 0,1 in flight; wait slot 0; publish
  STAGE(0); STAGE(1);
  asm volatile("s_waitcnt vmcnt(3)");
  __builtin_amdgcn_s_barrier();
  __builtin_amdgcn_sched_barrier(0);

#pragma unroll 1
  for (int kt = 0; kt < NKT; ++kt) {
    const uint8_t* sa = &As[0][0] + (kt % 3) * 16384;
    const uint8_t* sb = &Bs[0][0] + (kt % 3) * 8192;

    // grouped fragment reads: 4 lo-granule b128s, then 4 hi (same footprint)
    i32x4 a0l = *(const i32x4*)(sa + offA[0]);
    i32x4 a1l = *(const i32x4*)(sa + offA[1]);
    i32x4 b0l = *(const i32x4*)(sb + offB[0]);
    i32x4 b1l = *(const i32x4*)(sb + offB[1]);
    i32x4 a0h = *(const i32x4*)(sa + (offA[0] ^ 16));
    i32x4 a1h = *(const i32x4*)(sa + (offA[1] ^ 16));
    i32x4 b0h = *(const i32x4*)(sb + (offB[0] ^ 16));
    i32x4 b1h = *(const i32x4*)(sb + (offB[1] ^ 16));

    if (kt + 2 < NKT) {
      STAGE(kt + 2);
      asm volatile("s_waitcnt vmcnt(3)");   // slot kt+1 landed (own loads)
    } else {
      asm volatile("s_waitcnt vmcnt(0)");
    }

    const i32x8 A0 = cat8(a0l, a0h), A1 = cat8(a1l, a1h);
    const i32x8 B0 = cat8(b0l, b0h), B1 = cat8(b1l, b1h);
    __builtin_amdgcn_s_setprio(1);
    acc[0][0] = __builtin_amdgcn_mfma_scale_f32_32x32x64_f8f6f4(
        A0, B0, acc[0][0], 0, 0, 0, SCL, 0, SCL);
    acc[0][1] = __builtin_amdgcn_mfma_scale_f32_32x32x64_f8f6f4(
        A0, B1, acc[0][1], 0, 0, 0, SCL, 0, SCL);
    acc[1][0] = __builtin_amdgcn_mfma_scale_f32_32x32x64_f8f6f4(
        A1, B0, acc[1][0], 0, 0, 0, SCL, 0, SCL);
    acc[1][1] = __builtin_amdgcn_mfma_scale_f32_32x32x64_f8f6f4(
        A1, B1, acc[1][1], 0, 0, 0, SCL, 0, SCL);
    __builtin_amdgcn_s_setprio(0);

    __builtin_amdgcn_s_barrier();           // slot kt+1 visible to all waves
    __builtin_amdgcn_sched_barrier(0);
  }

#undef STAGE

  // ---------- epilogue (full gram, every pair once) ----------
  float sqc[2], rnc[2];
  int   yc[2];
#pragma unroll
  for (int nb = 0; nb < 2; ++nb) {
    const int gj = bj * 128 + wc * 64 + nb * 32 + r32;
    sqc[nb] = sq[gj]; rnc[nb] = rn[gj]; yc[nb] = y[gj];
  }
  float lsum = 0.f;
#pragma unroll
  for (int mt = 0; mt < 2; ++mt) {
#pragma unroll
    for (int e = 0; e < 16; ++e) {
      const int gi = bi * 256 + wr * 64 + mt * 32 + (e & 3) + 8 * (e >> 2) + 4 * kg;
      const float sqi = sq[gi], rni = rn[gi];
      const int yi = y[gi];
#pragma unroll
      for (int nb = 0; nb < 2; ++nb) {
        const float g  = acc[mt][nb][e];
        const float d2 = sqi + sqc[nb] - 2.0f * g;
        const float dist = d2 > 0.f ? sqrtf(d2) : 0.f;
        const float sim  = g * rni * rnc[nb];
        lsum += (yi == yc[nb]) ? (dist - sim) : (sim - dist);
      }
    }
  }
#pragma unroll
  for (int off = 32; off; off >>= 1) lsum += __shfl_down(lsum, off);
  __shared__ float wsum[8];
  if (lane == 0) wsum[wid] = lsum;
  __syncthreads();
  if (tid == 0) {
    float t = 0.f;
#pragma unroll
    for (int i = 0; i < 8; ++i) t += wsum[i];
    partials[blockIdx.x] = t;
  }
}

// ---------------- deterministic final reduce ----------------
extern "C" __global__ void __launch_bounds__(256) reduce_kernel(
    const float* __restrict__ partials, float* __restrict__ out) {
  float s = 0.f;
  for (int i = threadIdx.x; i < GBLK; i += 256) s += partials[i];
#pragma unroll
  for (int off = 32; off; off >>= 1) s += __shfl_down(s, off);
  __shared__ float ws[4];
  if ((threadIdx.x & 63) == 0) ws[threadIdx.x >> 6] = s;
  __syncthreads();
  if (threadIdx.x == 0) out[0] = ws[0] + ws[1] + ws[2] + ws[3];
}

extern "C" void kernel_launch(void* const* d_in, const int* in_sizes, int n_in,
                              void* d_out, int out_size, void* d_ws, size_t ws_size,
                              hipStream_t stream) {
  const float* F = (const float*)d_in[0];
  const int*   y = (const int*)d_in[1];
  float* out = (float*)d_out;

  uint8_t* Fb = (uint8_t*)d_ws;                               // 4 MB fp8
  float*  sq = (float*)((char*)d_ws + (size_t)NROWS * DDIM);
  float*  rn = sq + NROWS;
  float*  partials = rn + NROWS;

  prep_kernel<<<NROWS / 4, 256, 0, stream>>>(F, Fb, sq, rn);
  gram_kernel<<<GBLK, 512, 0, stream>>>(Fb, sq, rn, y, partials);
  reduce_kernel<<<1, 256, 0, stream>>>(partials, out);
}